// Round 3
// baseline (142.866 us; speedup 1.0000x reference)
//
#include <hip/hip_runtime.h>
#include <hip/hip_bf16.h>
#include <stdint.h>

#define VOCAB 200000
#define EDIM 128
#define NTREES 2048
#define KNODES 511

typedef __attribute__((ext_vector_type(4))) float f32x4;
typedef __attribute__((ext_vector_type(8))) short s16x8;
typedef __attribute__((ext_vector_type(8))) unsigned short u16x8;

__device__ __forceinline__ unsigned short f2bf(float x) {
  unsigned u = __builtin_bit_cast(unsigned, x);
  return (unsigned short)((u + 0x7fffu + ((u >> 16) & 1u)) >> 16);  // RNE
}
__device__ __forceinline__ float bf2f(unsigned short h) {
  unsigned u = ((unsigned)h) << 16;
  return __builtin_bit_cast(float, u);
}

// ---- manual OCP e4m3fn codec (values pre-scaled x64 so sigma~1, |v| << 448) ----
__device__ __forceinline__ unsigned fp8enc(float v) {
  unsigned u = __builtin_bit_cast(unsigned, v);
  unsigned s = (u >> 24) & 0x80u;
  unsigned au = u & 0x7fffffffu;
  au = au > 0x43E00000u ? 0x43E00000u : au;            // clamp to 448
  unsigned r = au + 0x0007ffffu + ((au >> 20) & 1u);   // RNE to 3 mantissa bits
  unsigned code = (((r >> 23) - 120u) << 3) | ((r >> 20) & 7u);
  float a = __builtin_bit_cast(float, au);
  unsigned sub = (unsigned)(int)rintf(a * 512.0f);     // subnormal: multiples of 2^-9
  unsigned c = (au < 0x3C800000u) ? sub : code;        // 2^-6 boundary
  return c | s;
}
__device__ __forceinline__ float fp8dec(unsigned b) {
  unsigned e = (b >> 3) & 15u, m = b & 7u;
  float n = __builtin_bit_cast(float, ((e + 120u) << 23) | (m << 20));
  float sv = (float)(int)m * 0.001953125f;             // m * 2^-9
  float v = e ? n : sv;
  return (b & 0x80u) ? -v : v;
}

// ---------------- Kernel 1: T8[v][d] = fp8( 64*(emb[v,:]@W[:,d] + b[d]) ) ----------------
// Operand-swapped MFMA: A = W^T tile (from LDS, same read as before), B = emb^T tile
// (same global read). D then gives lane 4 CONSECUTIVE out-cols of ONE vocab row ->
// pack 4 fp8 -> u32 -> coalesced stores (16 store instrs/wave vs 128 2B-scatters).
__global__ __launch_bounds__(256) void proj_kernel(
    const float* __restrict__ emb, const float* __restrict__ W,
    const float* __restrict__ bias, unsigned char* __restrict__ T8) {
  __shared__ unsigned short WT[EDIM][136];  // [col][k], pitch 136 breaks bank stride
  __shared__ float bsh[EDIM];

  const int tid = threadIdx.x;
  for (int idx = tid; idx < EDIM * EDIM; idx += 256) {
    int k = idx >> 7, n = idx & 127;      // W is [k][n] row-major
    WT[n][k] = f2bf(W[idx] * 64.0f);      // fold fp8 scale into W
  }
  if (tid < EDIM) bsh[tid] = bias[tid] * 64.0f;
  __syncthreads();

  const int w = tid >> 6, lane = tid & 63;
  const int q = lane >> 4, cl = lane & 15;
  const long rowbase = (long)blockIdx.x * 128 + (long)w * 32;

  f32x4 acc[2][8];
#pragma unroll
  for (int rt = 0; rt < 2; ++rt)
#pragma unroll
    for (int nt = 0; nt < 8; ++nt) acc[rt][nt] = (f32x4){0.f, 0.f, 0.f, 0.f};

#pragma unroll
  for (int ks = 0; ks < 4; ++ks) {
    const int k0 = ks * 32 + q * 8;
    s16x8 ef[2];
#pragma unroll
    for (int rt = 0; rt < 2; ++rt) {
      long r = rowbase + rt * 16 + cl;
      if (r >= VOCAB) r = VOCAB - 1;      // tail clamp (dup loads, stores masked)
      const float* ap = emb + r * EDIM + k0;
      f32x4 a0 = *(const f32x4*)ap;
      f32x4 a1 = *(const f32x4*)(ap + 4);
      u16x8 t;
      t[0] = f2bf(a0[0]); t[1] = f2bf(a0[1]); t[2] = f2bf(a0[2]); t[3] = f2bf(a0[3]);
      t[4] = f2bf(a1[0]); t[5] = f2bf(a1[1]); t[6] = f2bf(a1[2]); t[7] = f2bf(a1[3]);
      ef[rt] = __builtin_bit_cast(s16x8, t);
    }
#pragma unroll
    for (int nt = 0; nt < 8; ++nt) {
      s16x8 wf = *(const s16x8*)&WT[nt * 16 + cl][k0];
#pragma unroll
      for (int rt = 0; rt < 2; ++rt)   // A=W^T (M=out-col), B=emb^T (N=vocab-row)
        acc[rt][nt] = __builtin_amdgcn_mfma_f32_16x16x32_bf16(wf, ef[rt], acc[rt][nt], 0, 0, 0);
    }
  }

  // D[m][n]: m = 4q+r = out-col within nt tile, n = cl = vocab row within rt tile.
#pragma unroll
  for (int rt = 0; rt < 2; ++rt) {
    long row = rowbase + rt * 16 + cl;
    if (row < VOCAB) {
#pragma unroll
      for (int nt = 0; nt < 8; ++nt) {
        const int col0 = nt * 16 + q * 4;
        unsigned pk = 0;
#pragma unroll
        for (int r = 0; r < 4; ++r) {
          float f = acc[rt][nt][r] + bsh[col0 + r];
          pk |= fp8enc(f) << (8 * r);
        }
        *(unsigned*)&T8[row * EDIM + col0] = pk;
      }
    }
  }
}

// ---------------- Kernel 2: per-(tree,half) gather + bottom-up sums + max ----------------
// P8: 511 gathered fp8 half-rows (one quantization per node). PS: internal-node
// bf16 sums (scaled x64). Gather bytes halved vs bf16 (fabric-BW-bound at ~3.5 TB/s).
__global__ __launch_bounds__(512) void tree_kernel(
    const unsigned char* __restrict__ T8, const int* __restrict__ tokens,
    float* __restrict__ out) {
  __shared__ unsigned char P8[512][64];    // 32 KiB
  __shared__ unsigned short PS[256][64];   // 32 KiB

  const int tid = threadIdx.x;
  const int bid = blockIdx.x;
  const int tree = bid & (NTREES - 1);
  const int half = bid >> 11;              // dims [0,64) or [64,128)
  const int wv = tid >> 6, lane = tid & 63;

  // --- gather: 4 LDS-DMA instrs/wave, each 16 rows x 64B (dest linear) ---
  const int* tk = tokens + (long)tree * KNODES;
  int toks[4];
#pragma unroll
  for (int i = 0; i < 4; ++i) {
    int node = wv * 64 + i * 16 + (lane >> 2);
    toks[i] = tk[node > 510 ? 510 : node];
  }
#pragma unroll
  for (int i = 0; i < 4; ++i) {
    const unsigned char* src = T8 + (long)toks[i] * EDIM + half * 64 + (lane & 3) * 16;
    unsigned char* dst = &P8[wv * 64 + i * 16][0];  // wave-uniform; HW adds lane*16
    __builtin_amdgcn_global_load_lds(
        (const __attribute__((address_space(1))) unsigned int*)src,
        (__attribute__((address_space(3))) unsigned int*)dst, 16, 0, 0);
  }
  __syncthreads();

  const int c = tid & 7, g = tid >> 3;     // c: 8-dim chunk, g: node group (64)
  float rmax[8];
#pragma unroll
  for (int e = 0; e < 8; ++e) rmax[e] = 0.f;  // 0-init folds the final ReLU clamp

  // level 7: parent + both children from fp8; write bf16 sum to PS
#pragma unroll
  for (int j0 = 0; j0 < 2; ++j0) {
    const int m = 127 + j0 * 64 + g;
    uint2 pr = *(const uint2*)&P8[m][c * 8];
    uint2 xr = *(const uint2*)&P8[2 * m + 1][c * 8];
    uint2 yr = *(const uint2*)&P8[2 * m + 2][c * 8];
    u16x8 sp;
#pragma unroll
    for (int e = 0; e < 8; ++e) {
      unsigned sh = 8 * (e & 3);
      float pv = fp8dec(((e < 4 ? pr.x : pr.y) >> sh) & 0xFFu);
      float x = fp8dec(((e < 4 ? xr.x : xr.y) >> sh) & 0xFFu);
      float y = fp8dec(((e < 4 ? yr.x : yr.y) >> sh) & 0xFFu);
      float sv = pv + x + y;
      rmax[e] = fmaxf(rmax[e], fmaxf(fmaxf(x, y), sv));
      sp[e] = f2bf(sv);
    }
    *(u16x8*)&PS[m][c * 8] = sp;
  }
  __syncthreads();

  // levels 6..0: parent from fp8, children from bf16 PS
  for (int l = 6; l >= 0; --l) {
    const int cnt = 1 << l;
    if (g < cnt) {
      const int m = cnt - 1 + g;
      uint2 pr = *(const uint2*)&P8[m][c * 8];
      u16x8 c1 = *(const u16x8*)&PS[2 * m + 1][c * 8];
      u16x8 c2 = *(const u16x8*)&PS[2 * m + 2][c * 8];
      u16x8 sp;
#pragma unroll
      for (int e = 0; e < 8; ++e) {
        float pv = fp8dec(((e < 4 ? pr.x : pr.y) >> (8 * (e & 3))) & 0xFFu);
        float x = bf2f(c1[e]), y = bf2f(c2[e]);
        float sv = pv + x + y;
        rmax[e] = fmaxf(rmax[e], fmaxf(fmaxf(x, y), sv));
        sp[e] = f2bf(sv);
      }
      *(u16x8*)&PS[m][c * 8] = sp;
    }
    __syncthreads();
  }

  // --- max reduce across 64 node-groups (overlay on dead P8) ---
  float* mb = (float*)&P8[0][0];  // 64*64*4 = 16 KiB <= 32 KiB
#pragma unroll
  for (int e = 0; e < 8; ++e) mb[g * 64 + c * 8 + e] = rmax[e];
  __syncthreads();
  if (tid < 64) {
    float v = mb[tid];
#pragma unroll 4
    for (int g2 = 1; g2 < 64; ++g2) v = fmaxf(v, mb[g2 * 64 + tid]);
    out[(long)tree * 128 + half * 64 + tid] = v * 0.015625f;  // /64 exact
  }
}

extern "C" void kernel_launch(void* const* d_in, const int* in_sizes, int n_in,
                              void* d_out, int out_size, void* d_ws, size_t ws_size,
                              hipStream_t stream) {
  const float* emb = (const float*)d_in[0];
  const float* W = (const float*)d_in[1];
  const float* b = (const float*)d_in[2];
  const int* tokens = (const int*)d_in[3];
  // d_in[4..6] (parent/level/batch_id) are structural — recomputed from index math.

  unsigned char* T8 = (unsigned char*)d_ws;  // 200000*128 = 25.6 MB scratch
  float* out = (float*)d_out;

  const int nblk1 = (VOCAB + 127) / 128;  // 1563
  proj_kernel<<<nblk1, 256, 0, stream>>>(emb, W, b, T8);
  tree_kernel<<<NTREES * 2, 512, 0, stream>>>(T8, tokens, out);
}

// Round 4
// 74.482 us; speedup vs baseline: 1.9181x; 1.9181x over previous
//
#include <hip/hip_runtime.h>
#include <hip/hip_bf16.h>
#include <stdint.h>

#define VOCAB 200000
#define EDIM 128
#define NTREES 2048
#define KNODES 511

typedef __attribute__((ext_vector_type(4))) float f32x4;
typedef __attribute__((ext_vector_type(2))) float f32x2;
typedef __attribute__((ext_vector_type(8))) short s16x8;
typedef __attribute__((ext_vector_type(8))) unsigned short u16x8;

__device__ __forceinline__ unsigned short f2bf(float x) {
  unsigned u = __builtin_bit_cast(unsigned, x);
  return (unsigned short)((u + 0x7fffu + ((u >> 16) & 1u)) >> 16);  // RNE
}
__device__ __forceinline__ float bf2f(unsigned short h) {
  unsigned u = ((unsigned)h) << 16;
  return __builtin_bit_cast(float, u);
}

// ---- manual OCP e4m3fn codec (values pre-scaled x64; encoder used by proj) ----
__device__ __forceinline__ unsigned fp8enc(float v) {
  unsigned u = __builtin_bit_cast(unsigned, v);
  unsigned s = (u >> 24) & 0x80u;
  unsigned au = u & 0x7fffffffu;
  au = au > 0x43E00000u ? 0x43E00000u : au;            // clamp to 448
  unsigned r = au + 0x0007ffffu + ((au >> 20) & 1u);   // RNE to 3 mantissa bits
  unsigned code = (((r >> 23) - 120u) << 3) | ((r >> 20) & 7u);
  float a = __builtin_bit_cast(float, au);
  unsigned sub = (unsigned)(int)rintf(a * 512.0f);     // subnormal: multiples of 2^-9
  unsigned c = (au < 0x3C800000u) ? sub : code;        // 2^-6 boundary
  return c | s;
}
__device__ __forceinline__ float fp8dec(unsigned b) {
  unsigned e = (b >> 3) & 15u, m = b & 7u;
  float n = __builtin_bit_cast(float, ((e + 120u) << 23) | (m << 20));
  float sv = (float)(int)m * 0.001953125f;             // m * 2^-9
  float v = e ? n : sv;
  return (b & 0x80u) ? -v : v;
}

// decode 8 fp8 bytes -> 8 f32 (HW packed cvt when available)
__device__ __forceinline__ void dec8(uint2 v, float* o) {
#if __has_builtin(__builtin_amdgcn_cvt_pk_f32_fp8)
  f32x2 a = __builtin_amdgcn_cvt_pk_f32_fp8(v.x, false);
  f32x2 b = __builtin_amdgcn_cvt_pk_f32_fp8(v.x, true);
  f32x2 c = __builtin_amdgcn_cvt_pk_f32_fp8(v.y, false);
  f32x2 d = __builtin_amdgcn_cvt_pk_f32_fp8(v.y, true);
  o[0] = a[0]; o[1] = a[1]; o[2] = b[0]; o[3] = b[1];
  o[4] = c[0]; o[5] = c[1]; o[6] = d[0]; o[7] = d[1];
#else
#pragma unroll
  for (int i = 0; i < 4; ++i) o[i] = fp8dec((v.x >> (8 * i)) & 0xFFu);
#pragma unroll
  for (int i = 0; i < 4; ++i) o[4 + i] = fp8dec((v.y >> (8 * i)) & 0xFFu);
#endif
}

// ---------------- Kernel 1: T8[v][d] = fp8( 64*(emb[v,:]@W[:,d] + b[d]) ) ----------------
// (unchanged from R3 — operand-swapped MFMA, coalesced packed-u32 stores)
__global__ __launch_bounds__(256) void proj_kernel(
    const float* __restrict__ emb, const float* __restrict__ W,
    const float* __restrict__ bias, unsigned char* __restrict__ T8) {
  __shared__ unsigned short WT[EDIM][136];
  __shared__ float bsh[EDIM];

  const int tid = threadIdx.x;
  for (int idx = tid; idx < EDIM * EDIM; idx += 256) {
    int k = idx >> 7, n = idx & 127;      // W is [k][n] row-major
    WT[n][k] = f2bf(W[idx] * 64.0f);      // fold fp8 scale into W
  }
  if (tid < EDIM) bsh[tid] = bias[tid] * 64.0f;
  __syncthreads();

  const int w = tid >> 6, lane = tid & 63;
  const int q = lane >> 4, cl = lane & 15;
  const long rowbase = (long)blockIdx.x * 128 + (long)w * 32;

  f32x4 acc[2][8];
#pragma unroll
  for (int rt = 0; rt < 2; ++rt)
#pragma unroll
    for (int nt = 0; nt < 8; ++nt) acc[rt][nt] = (f32x4){0.f, 0.f, 0.f, 0.f};

#pragma unroll
  for (int ks = 0; ks < 4; ++ks) {
    const int k0 = ks * 32 + q * 8;
    s16x8 ef[2];
#pragma unroll
    for (int rt = 0; rt < 2; ++rt) {
      long r = rowbase + rt * 16 + cl;
      if (r >= VOCAB) r = VOCAB - 1;
      const float* ap = emb + r * EDIM + k0;
      f32x4 a0 = *(const f32x4*)ap;
      f32x4 a1 = *(const f32x4*)(ap + 4);
      u16x8 t;
      t[0] = f2bf(a0[0]); t[1] = f2bf(a0[1]); t[2] = f2bf(a0[2]); t[3] = f2bf(a0[3]);
      t[4] = f2bf(a1[0]); t[5] = f2bf(a1[1]); t[6] = f2bf(a1[2]); t[7] = f2bf(a1[3]);
      ef[rt] = __builtin_bit_cast(s16x8, t);
    }
#pragma unroll
    for (int nt = 0; nt < 8; ++nt) {
      s16x8 wf = *(const s16x8*)&WT[nt * 16 + cl][k0];
#pragma unroll
      for (int rt = 0; rt < 2; ++rt)   // A=W^T (M=out-col), B=emb^T (N=vocab-row)
        acc[rt][nt] = __builtin_amdgcn_mfma_f32_16x16x32_bf16(wf, ef[rt], acc[rt][nt], 0, 0, 0);
    }
  }

#pragma unroll
  for (int rt = 0; rt < 2; ++rt) {
    long row = rowbase + rt * 16 + cl;
    if (row < VOCAB) {
#pragma unroll
      for (int nt = 0; nt < 8; ++nt) {
        const int col0 = nt * 16 + q * 4;
        unsigned pk = 0;
#pragma unroll
        for (int r = 0; r < 4; ++r) {
          float f = acc[rt][nt][r] + bsh[col0 + r];
          pk |= fp8enc(f) << (8 * r);
        }
        *(unsigned*)&T8[row * EDIM + col0] = pk;
      }
    }
  }
}

// ---------------- Kernel 2: one block = one tree, full 128-dim fp8 rows ----------------
// P8[512][128] = 64 KiB (one gather request = one 128B line per node). Sums (bf16)
// overlaid on dead rows >=128 after a register-staged level-7 pass. 2 blocks/CU.
__global__ __launch_bounds__(512, 4) void tree_kernel(
    const unsigned char* __restrict__ T8, const int* __restrict__ tokens,
    float* __restrict__ out) {
  __shared__ unsigned char P8[512][EDIM];          // 64 KiB
  unsigned char* lds = &P8[0][0];
  const int SOFF = 16384;                          // S: 128 slots x 288 B (rows 128..415)
  const int MOFF = 53248;                          // mb: 8 x 128 f32 (rows 416..447)

  const int tid = threadIdx.x;
  const int tree = blockIdx.x;
  const int wv = tid >> 6, lane = tid & 63;

  // --- gather: 8 DMA instrs/wave, 8 rows x 8 lanes; source chunk-XOR swizzled ---
  const int* tk = tokens + (long)tree * KNODES;
  int toks[8];
#pragma unroll
  for (int i = 0; i < 8; ++i) {
    int node = wv * 64 + i * 8 + (lane >> 3);
    toks[i] = tk[node > 510 ? 510 : node];         // row 511 = dup, never read
  }
  const int chunk = (lane & 7) ^ ((lane >> 3) & 7);  // row&7 == lane>>3 here
#pragma unroll
  for (int i = 0; i < 8; ++i) {
    const unsigned char* src = T8 + (long)toks[i] * EDIM + chunk * 16;
    unsigned char* dst = &P8[wv * 64 + i * 8][0];  // wave-uniform; HW adds lane*16
    __builtin_amdgcn_global_load_lds(
        (const __attribute__((address_space(1))) unsigned int*)src,
        (__attribute__((address_space(3))) unsigned int*)dst, 16, 0, 0);
  }
  __syncthreads();

  // LDS chunk c of row r holds global chunk c^(r&7); to read global chunk g use g^(r&7).
  auto ldP8 = [&](int row, int q8) -> uint2 {      // 8 fp8 at dims q8*8
    int g = q8 >> 1, h = q8 & 1;
    return *(const uint2*)(lds + row * 128 + (((g ^ (row & 7))) << 4) + h * 8);
  };
  auto saddr = [&](int slot, int q16) -> unsigned char* {  // 16B chunk q16 of sum slot
    return lds + SOFF + slot * 288 + ((q16 ^ (slot & 7)) << 4);
  };

  const int q = tid & 15;          // dim chunk: dims q*8 .. q*8+7
  const int jg = tid >> 4;         // 0..31
  float rmax[8];
#pragma unroll
  for (int e = 0; e < 8; ++e) rmax[e] = 0.f;       // 0-init folds final ReLU clamp

  // --- level 7 (parents 127..254): register-staged (reads must precede overlay) ---
  u16x8 sp7[4];
#pragma unroll
  for (int k = 0; k < 4; ++k) {
    const int p = jg + 32 * k, m = 127 + p;
    uint2 pr = ldP8(m, q);
    uint2 xr = ldP8(2 * m + 1, q);
    uint2 yr = ldP8(2 * m + 2, q);
    float pv[8], xv[8], yv[8];
    dec8(pr, pv); dec8(xr, xv); dec8(yr, yv);
#pragma unroll
    for (int e = 0; e < 8; ++e) {
      float sv = pv[e] + xv[e] + yv[e];
      rmax[e] = fmaxf(rmax[e], fmaxf(fmaxf(xv[e], yv[e]), sv));  // leaves + sum
      sp7[k][e] = f2bf(sv);
    }
  }
  __syncthreads();                 // ALL level-7 reads done before overlay writes
#pragma unroll
  for (int k = 0; k < 4; ++k) *(u16x8*)saddr(jg + 32 * k, q) = sp7[k];
  __syncthreads();

  // --- levels 6..0: parent fp8 from P8 rows <127 (intact), children sums from S ---
  for (int l = 6; l >= 0; --l) {
    const int cnt = 1 << l;
    for (int p = jg; p < cnt; p += 32) {
      const int m = cnt - 1 + p;
      const int ps = p << (7 - l);
      const int c2s = ps + (1 << (6 - l));
      uint2 pr = ldP8(m, q);
      u16x8 c1 = *(const u16x8*)saddr(ps, q);
      u16x8 c2 = *(const u16x8*)saddr(c2s, q);
      float pv[8];
      dec8(pr, pv);
      u16x8 sp;
#pragma unroll
      for (int e = 0; e < 8; ++e) {
        float sv = pv[e] + bf2f(c1[e]) + bf2f(c2[e]);
        rmax[e] = fmaxf(rmax[e], sv);              // children already tracked
        sp[e] = f2bf(sv);
      }
      *(u16x8*)saddr(ps, q) = sp;                  // overwrites own c1 slot (safe)
    }
    __syncthreads();
  }

  // --- final max: shuffle over jg within wave (lanes q,q+16,q+32,q+48), then LDS ---
#pragma unroll
  for (int e = 0; e < 8; ++e) {
    rmax[e] = fmaxf(rmax[e], __shfl_xor(rmax[e], 16, 64));
    rmax[e] = fmaxf(rmax[e], __shfl_xor(rmax[e], 32, 64));
  }
  float* mb = (float*)(lds + MOFF);
  if (lane < 16) {
#pragma unroll
    for (int e = 0; e < 8; ++e) mb[wv * 128 + lane * 8 + e] = rmax[e];
  }
  __syncthreads();
  if (tid < 128) {
    float v = mb[tid];
#pragma unroll
    for (int w2 = 1; w2 < 8; ++w2) v = fmaxf(v, mb[w2 * 128 + tid]);
    out[(long)tree * 128 + tid] = v * 0.015625f;   // /64 exact
  }
}

extern "C" void kernel_launch(void* const* d_in, const int* in_sizes, int n_in,
                              void* d_out, int out_size, void* d_ws, size_t ws_size,
                              hipStream_t stream) {
  const float* emb = (const float*)d_in[0];
  const float* W = (const float*)d_in[1];
  const float* b = (const float*)d_in[2];
  const int* tokens = (const int*)d_in[3];
  // d_in[4..6] (parent/level/batch_id) are structural — recomputed from index math.

  unsigned char* T8 = (unsigned char*)d_ws;  // 200000*128 = 25.6 MB scratch
  float* out = (float*)d_out;

  const int nblk1 = (VOCAB + 127) / 128;  // 1563
  proj_kernel<<<nblk1, 256, 0, stream>>>(emb, W, b, T8);
  tree_kernel<<<NTREES, 512, 0, stream>>>(T8, tokens, out);
}